// Round 1
// baseline (384.561 us; speedup 1.0000x reference)
//
#include <hip/hip_runtime.h>
#include <hip/hip_bf16.h>

#define N 1024
#define D 64
#define H1 128
#define H1P 132   // padded LDS stride (floats), keeps float4 alignment, kills bank conflicts
#define H2 64
#define FLAG_CAP 65536
#define FLAG_THRESH 5e-3f

// ---------------------------------------------------------------------------
// K1: A' = X @ W1[:64,:] + b1   (1024 x 128)
//     B  = X @ W1[64:,:]        (1024 x 128)
// ---------------------------------------------------------------------------
__global__ __launch_bounds__(128) void precompute_kernel(
    const float* __restrict__ X, const float* __restrict__ W1,
    const float* __restrict__ b1, float* __restrict__ Ap, float* __restrict__ Bp)
{
    int i = blockIdx.x;
    int k = threadIdx.x;
    float a = b1[k];
    float b = 0.f;
    for (int c = 0; c < D; ++c) {
        float x = X[i * D + c];                 // wave-uniform -> s_load
        a = fmaf(x, W1[c * H1 + k], a);
        b = fmaf(x, W1[(D + c) * H1 + k], b);
    }
    Ap[i * H1 + k] = a;
    Bp[i * H1 + k] = b;
}

// ---------------------------------------------------------------------------
// K2: d[i][j] = sum_o relu( sum_k relu(A'[i][k]+B[j][k]) * W2[k][o] + b2[o] ) * (W3[o][1]-W3[o][0])
//              + (b3[1]-b3[0])
// lane-per-pair: 16x16 pair tile per 256-thread block; W2 via uniform (scalar) loads.
// ---------------------------------------------------------------------------
__global__ __launch_bounds__(256) void pair_mlp_kernel(
    const float* __restrict__ Ap, const float* __restrict__ Bp,
    const float* __restrict__ W2, const float* __restrict__ b2,
    const float* __restrict__ W3, const float* __restrict__ b3,
    float* __restrict__ dmat)
{
    __shared__ float As[16][H1P];
    __shared__ float Bs[16][H1P];

    int bi = blockIdx.x;
    int ti = (bi >> 6) << 4;     // i0 of tile (grid = 64 x 64 tiles)
    int tj = (bi & 63) << 4;     // j0 of tile
    int tid = threadIdx.x;

    // stage A' rows [ti..ti+15], B rows [tj..tj+15] (2048 floats each = 512 float4)
    #pragma unroll
    for (int it = 0; it < 2; ++it) {
        int v = tid + it * 256;          // 0..511
        int row = v >> 5;                // 16 rows, 32 float4/row
        int col = (v & 31) << 2;
        *(float4*)&As[row][col] = *(const float4*)&Ap[(ti + row) * H1 + col];
        *(float4*)&Bs[row][col] = *(const float4*)&Bp[(tj + row) * H1 + col];
    }
    __syncthreads();

    int lane = tid & 63;
    int li = lane >> 4;                  // 0..3
    int lj = lane & 15;                  // 0..15
    int wave = tid >> 6;                 // 0..3
    int i_loc = (wave << 2) + li;        // 0..15

    const float* arow = &As[i_loc][0];
    const float* brow = &Bs[lj][0];

    float dacc = 0.f;
    #pragma unroll
    for (int half = 0; half < 2; ++half) {
        float acc[32];
        #pragma unroll
        for (int o = 0; o < 32; ++o) acc[o] = 0.f;

        #pragma unroll 2
        for (int k = 0; k < H1; k += 4) {
            float4 a4 = *(const float4*)&arow[k];
            float4 b4 = *(const float4*)&brow[k];
            float h0 = fmaxf(a4.x + b4.x, 0.f);
            float h1 = fmaxf(a4.y + b4.y, 0.f);
            float h2 = fmaxf(a4.z + b4.z, 0.f);
            float h3 = fmaxf(a4.w + b4.w, 0.f);
            #pragma unroll
            for (int o = 0; o < 32; ++o) {
                int oo = half * 32 + o;  // uniform index -> s_load of W2
                acc[o] = fmaf(h0, W2[(k + 0) * H2 + oo], acc[o]);
                acc[o] = fmaf(h1, W2[(k + 1) * H2 + oo], acc[o]);
                acc[o] = fmaf(h2, W2[(k + 2) * H2 + oo], acc[o]);
                acc[o] = fmaf(h3, W2[(k + 3) * H2 + oo], acc[o]);
            }
        }
        #pragma unroll
        for (int o = 0; o < 32; ++o) {
            int oo = half * 32 + o;
            float h2v = fmaxf(acc[o] + b2[oo], 0.f);
            dacc = fmaf(h2v, W3[oo * 2 + 1] - W3[oo * 2 + 0], dacc);
        }
    }
    dacc += b3[1] - b3[0];
    dmat[(ti + i_loc) * N + (tj + lj)] = dacc;
}

// ---------------------------------------------------------------------------
// K3: D = 0.5*(d[i][j] + d[j][i]) + (g1 - g0);  out = D > 0;  flag |D| < thresh
// ---------------------------------------------------------------------------
__global__ __launch_bounds__(256) void epilogue_kernel(
    const float* __restrict__ dmat, const float* __restrict__ u,
    float* __restrict__ out, unsigned int* __restrict__ cnt,
    unsigned int* __restrict__ list)
{
    __shared__ float T1[32][33];
    __shared__ float T2[32][33];
    int bi = blockIdx.x >> 5;
    int bj = blockIdx.x & 31;
    int i0 = bi * 32, j0 = bj * 32;
    int tid = threadIdx.x;
    int r = tid >> 3;
    int c4 = (tid & 7) << 2;
    *(float4*)&T1[r][c4] = *(const float4*)&dmat[(i0 + r) * N + j0 + c4];
    *(float4*)&T2[r][c4] = *(const float4*)&dmat[(j0 + r) * N + i0 + c4];
    __syncthreads();

    int a = tid >> 3;
    int b0 = (tid & 7) << 2;
    #pragma unroll
    for (int q = 0; q < 4; ++q) {
        int b = b0 + q;
        int i = i0 + a, j = j0 + b;
        int ij = i * N + j;
        float2 uv = *(const float2*)&u[((size_t)ij) << 1];
        float g0 = -logf(-logf(uv.x + 1e-10f) + 1e-10f);
        float g1 = -logf(-logf(uv.y + 1e-10f) + 1e-10f);
        float Dv = 0.5f * (T1[a][b] + T2[b][a]) + (g1 - g0);
        out[ij] = Dv > 0.f ? 1.f : 0.f;
        if (fabsf(Dv) < FLAG_THRESH) {
            unsigned int idx = atomicAdd(cnt, 1u);
            if (idx < FLAG_CAP) list[idx] = (unsigned int)ij;
        }
    }
}

// ---------------------------------------------------------------------------
// K4: f64 repair of borderline entries. One wave per flagged (i,j).
// ---------------------------------------------------------------------------
__global__ __launch_bounds__(256) void repair_kernel(
    const float* __restrict__ X, const float* __restrict__ W1,
    const float* __restrict__ b1, const float* __restrict__ W2,
    const float* __restrict__ b2, const float* __restrict__ W3,
    const float* __restrict__ b3, const float* __restrict__ u,
    float* __restrict__ out, const unsigned int* __restrict__ cnt,
    const unsigned int* __restrict__ list)
{
    __shared__ double h1s[4][2][H1];
    int tid = threadIdx.x;
    int lane = tid & 63;
    int wave = tid >> 6;
    unsigned int n = *cnt;
    if (n > FLAG_CAP) n = FLAG_CAP;
    int gw = blockIdx.x * 4 + wave;
    int TW = gridDim.x * 4;
    int iters = (int)((n + TW - 1) / TW);
    double w3d = (double)W3[lane * 2 + 1] - (double)W3[lane * 2 + 0];

    for (int t = 0; t < iters; ++t) {
        int f = gw + t * TW;
        bool active = f < (int)n;
        int ij = active ? (int)list[f] : 0;
        int i = ij >> 10, j = ij & (N - 1);
        if (active) {
            double ha0 = (double)b1[lane], ha1 = (double)b1[lane + 64];
            double hb0 = ha0, hb1 = ha1;
            for (int c = 0; c < D; ++c) {
                double xi = (double)X[i * D + c];
                double xj = (double)X[j * D + c];
                double wt0 = (double)W1[c * H1 + lane];
                double wt1 = (double)W1[c * H1 + lane + 64];
                double wb0 = (double)W1[(D + c) * H1 + lane];
                double wb1 = (double)W1[(D + c) * H1 + lane + 64];
                ha0 += xi * wt0 + xj * wb0;
                ha1 += xi * wt1 + xj * wb1;
                hb0 += xj * wt0 + xi * wb0;
                hb1 += xj * wt1 + xi * wb1;
            }
            h1s[wave][0][lane]      = ha0 > 0.0 ? ha0 : 0.0;
            h1s[wave][0][lane + 64] = ha1 > 0.0 ? ha1 : 0.0;
            h1s[wave][1][lane]      = hb0 > 0.0 ? hb0 : 0.0;
            h1s[wave][1][lane + 64] = hb1 > 0.0 ? hb1 : 0.0;
        }
        __syncthreads();
        double da = 0.0, db = 0.0;
        if (active) {
            double sa = (double)b2[lane], sb = sa;
            for (int k = 0; k < H1; ++k) {
                double w = (double)W2[k * H2 + lane];
                sa += h1s[wave][0][k] * w;
                sb += h1s[wave][1][k] * w;
            }
            if (sa < 0.0) sa = 0.0;
            if (sb < 0.0) sb = 0.0;
            da = sa * w3d;
            db = sb * w3d;
        }
        #pragma unroll
        for (int off = 32; off > 0; off >>= 1) {
            da += __shfl_down(da, off, 64);
            db += __shfl_down(db, off, 64);
        }
        if (active && lane == 0) {
            double b3d = (double)b3[1] - (double)b3[0];
            double u0 = (double)u[(((size_t)ij) << 1) + 0];
            double u1 = (double)u[(((size_t)ij) << 1) + 1];
            double g0 = -log(-log(u0 + 1e-10) + 1e-10);
            double g1 = -log(-log(u1 + 1e-10) + 1e-10);
            double Dv = 0.5 * (da + db) + b3d + (g1 - g0);
            out[ij] = Dv > 0.0 ? 1.f : 0.f;
        }
        __syncthreads();
    }
}

// ---------------------------------------------------------------------------
extern "C" void kernel_launch(void* const* d_in, const int* in_sizes, int n_in,
                              void* d_out, int out_size, void* d_ws, size_t ws_size,
                              hipStream_t stream) {
    const float* X  = (const float*)d_in[0];
    const float* W1 = (const float*)d_in[1];
    const float* b1 = (const float*)d_in[2];
    const float* W2 = (const float*)d_in[3];
    const float* b2 = (const float*)d_in[4];
    const float* W3 = (const float*)d_in[5];
    const float* b3 = (const float*)d_in[6];
    const float* u  = (const float*)d_in[7];
    float* out = (float*)d_out;

    // workspace layout
    float* dmat = (float*)d_ws;                        // 4 MB
    float* Ap   = dmat + (size_t)N * N;                // 512 KB
    float* Bp   = Ap + (size_t)N * H1;                 // 512 KB
    unsigned int* cnt  = (unsigned int*)(Bp + (size_t)N * H1);
    unsigned int* list = cnt + 4;                      // 256 KB

    hipMemsetAsync(cnt, 0, sizeof(unsigned int), stream);

    precompute_kernel<<<N, 128, 0, stream>>>(X, W1, b1, Ap, Bp);
    pair_mlp_kernel<<<(N / 16) * (N / 16), 256, 0, stream>>>(Ap, Bp, W2, b2, W3, b3, dmat);
    epilogue_kernel<<<(N / 32) * (N / 32), 256, 0, stream>>>(dmat, u, out, cnt, list);
    repair_kernel<<<64, 256, 0, stream>>>(X, W1, b1, W2, b2, W3, b3, u, out, cnt, list);
}

// Round 2
// 219.487 us; speedup vs baseline: 1.7521x; 1.7521x over previous
//
#include <hip/hip_runtime.h>
#include <hip/hip_bf16.h>

#define N 1024
#define D 64
#define H1 128
#define H2 64
#define FLAG_CAP 65536
#define FLAG_THRESH 0.015f
#define H1PAD 136   // f16 LDS row stride: 272 B = 17*16B (aligned b128, 2-way banks only)

typedef _Float16 half8 __attribute__((ext_vector_type(8)));
typedef float float4v __attribute__((ext_vector_type(4)));

// ---------------------------------------------------------------------------
// K1: pre-activations, exact f64 + f16 copies.
//   A = X @ W1[:64,:] + b1   (1024 x 128)
//   B = X @ W1[64:,:]        (1024 x 128)
// ---------------------------------------------------------------------------
__global__ __launch_bounds__(128) void precompute_kernel(
    const float* __restrict__ X, const float* __restrict__ W1,
    const float* __restrict__ b1,
    double* __restrict__ A64, double* __restrict__ B64,
    _Float16* __restrict__ A16, _Float16* __restrict__ B16)
{
    int i = blockIdx.x;
    int k = threadIdx.x;
    double a = (double)b1[k];
    double b = 0.0;
    for (int c = 0; c < D; ++c) {
        double x = (double)X[i * D + c];              // wave-uniform
        a += x * (double)W1[c * H1 + k];
        b += x * (double)W1[(D + c) * H1 + k];
    }
    A64[i * H1 + k] = a;
    B64[i * H1 + k] = b;
    A16[i * H1 + k] = (_Float16)(float)a;
    B16[i * H1 + k] = (_Float16)(float)b;
}

// ---------------------------------------------------------------------------
// K2: MFMA pair-MLP. Block = 16 i-rows x 64 j-cols = 1024 pairs.
// GEMM: M=pairs, K=128 (h = relu(A16[i]+B16[j]) generated on the fly),
//       N=64 (W2 resident in VGPRs as B-frags), layer-3 fused in epilogue.
// dmat[i][j] = sum_o relu(s_o + b2_o) * (W3[o][1]-W3[o][0])   (+b3 diff later)
// ---------------------------------------------------------------------------
__global__ __launch_bounds__(256, 4) void pair_mlp_kernel(
    const _Float16* __restrict__ A16, const _Float16* __restrict__ B16,
    const float* __restrict__ W2, const float* __restrict__ b2,
    const float* __restrict__ W3, float* __restrict__ dmat)
{
    __shared__ _Float16 As16[16 * H1PAD];
    __shared__ _Float16 Bs16[64 * H1PAD];
    __shared__ _Float16 W2t[64 * H1PAD];   // transposed: W2t[n][k]

    int tid = threadIdx.x;
    int it = blockIdx.x >> 4;      // 0..63
    int jt = blockIdx.x & 15;      // 0..15
    int ti = it << 4;              // i0
    int tj = jt << 6;              // j0

    // ---- stage A16 rows (16x128 f16): 8 f16 per thread
    {
        int row = tid >> 4;
        int col = (tid & 15) << 3;
        *(half8*)&As16[row * H1PAD + col] =
            *(const half8*)&A16[(size_t)(ti + row) * H1 + col];
    }
    // ---- stage B16 rows (64x128 f16): 32 f16 per thread
    #pragma unroll
    for (int r = 0; r < 4; ++r) {
        int v = tid + r * 256;
        int row = v >> 4;
        int col = (v & 15) << 3;
        *(half8*)&Bs16[row * H1PAD + col] =
            *(const half8*)&B16[(size_t)(tj + row) * H1 + col];
    }
    // ---- stage W2 transposed to f16: W2t[n][k] = W2[k][n]
    #pragma unroll
    for (int r = 0; r < 32; ++r) {
        int idx = tid + r * 256;   // 0..8191
        int k = idx >> 6;
        int n = idx & 63;
        W2t[n * H1PAD + k] = (_Float16)W2[idx];
    }
    __syncthreads();

    int lane = tid & 63;
    int wave = tid >> 6;
    int quad = lane >> 4;          // 0..3
    int m = lane & 15;             // A-frag row / C col

    // ---- B-frags: W2 fully in registers. b[ks][nt]: k=quad*8+j+32*ks, n=m+16*nt
    half8 bfrag[4][4];
    #pragma unroll
    for (int ks = 0; ks < 4; ++ks)
        #pragma unroll
        for (int nt = 0; nt < 4; ++nt)
            bfrag[ks][nt] = *(const half8*)&W2t[(m + 16 * nt) * H1PAD + quad * 8 + 32 * ks];

    // ---- per-lane epilogue constants: o = m + 16*nt
    float b2f[4], w3df[4];
    #pragma unroll
    for (int nt = 0; nt < 4; ++nt) {
        int o = m + 16 * nt;
        b2f[nt] = b2[o];
        w3df[nt] = W3[o * 2 + 1] - W3[o * 2 + 0];
    }

    const half8 zero8 = {0, 0, 0, 0, 0, 0, 0, 0};

    // ---- 16 M-tiles of 16 pairs per wave (64 tiles per block)
    #pragma unroll 1
    for (int t = 0; t < 16; ++t) {
        int T = wave * 16 + t;     // 0..63
        int ii = T >> 2;           // local i row 0..15
        int jj0 = (T & 3) << 4;    // local j base 0,16,32,48

        float4v acc[4];
        #pragma unroll
        for (int nt = 0; nt < 4; ++nt) {
            float bv = b2f[nt];
            acc[nt] = (float4v){bv, bv, bv, bv};   // fold b2 into C init
        }

        #pragma unroll
        for (int ks = 0; ks < 4; ++ks) {
            half8 ha = *(const half8*)&As16[ii * H1PAD + quad * 8 + 32 * ks];          // broadcast
            half8 hb = *(const half8*)&Bs16[(jj0 + m) * H1PAD + quad * 8 + 32 * ks];
            half8 h = __builtin_elementwise_max(ha + hb, zero8);                        // relu, v_pk ops
            #pragma unroll
            for (int nt = 0; nt < 4; ++nt)
                acc[nt] = __builtin_amdgcn_mfma_f32_16x16x32_f16(h, bfrag[ks][nt], acc[nt], 0, 0, 0);
        }

        // ---- fused layer 3: p[reg] = sum_o relu(s)*w3d, reduce over cols (lane&15)
        float p[4];
        #pragma unroll
        for (int reg = 0; reg < 4; ++reg) {
            float s = 0.f;
            #pragma unroll
            for (int nt = 0; nt < 4; ++nt)
                s = fmaf(fmaxf(acc[nt][reg], 0.f), w3df[nt], s);
            p[reg] = s;
        }
        #pragma unroll
        for (int off = 1; off < 16; off <<= 1) {
            #pragma unroll
            for (int reg = 0; reg < 4; ++reg)
                p[reg] += __shfl_xor(p[reg], off, 64);
        }
        if (m == 0) {
            int row = ti + ii;
            int colb = tj + jj0 + quad * 4;
            #pragma unroll
            for (int reg = 0; reg < 4; ++reg)
                dmat[(size_t)row * N + colb + reg] = p[reg];
        }
    }
}

// ---------------------------------------------------------------------------
// K3: D = 0.5*(d[i][j]+d[j][i]) + b3d + (g1-g0); out = D > 0; flag |D|<thresh
// ---------------------------------------------------------------------------
__global__ __launch_bounds__(256) void epilogue_kernel(
    const float* __restrict__ dmat, const float* __restrict__ b3,
    const float* __restrict__ u,
    float* __restrict__ out, unsigned int* __restrict__ cnt,
    unsigned int* __restrict__ list)
{
    __shared__ float T1[32][33];
    __shared__ float T2[32][33];
    int bi = blockIdx.x >> 5;
    int bj = blockIdx.x & 31;
    int i0 = bi * 32, j0 = bj * 32;
    int tid = threadIdx.x;
    int r = tid >> 3;
    int c4 = (tid & 7) << 2;
    *(float4*)&T1[r][c4] = *(const float4*)&dmat[(size_t)(i0 + r) * N + j0 + c4];
    *(float4*)&T2[r][c4] = *(const float4*)&dmat[(size_t)(j0 + r) * N + i0 + c4];
    __syncthreads();

    float b3d = b3[1] - b3[0];
    int a = tid >> 3;
    int b0 = (tid & 7) << 2;
    #pragma unroll
    for (int q = 0; q < 4; ++q) {
        int b = b0 + q;
        int i = i0 + a, j = j0 + b;
        int ij = i * N + j;
        float2 uv = *(const float2*)&u[((size_t)ij) << 1];
        float g0 = -logf(-logf(uv.x + 1e-10f) + 1e-10f);
        float g1 = -logf(-logf(uv.y + 1e-10f) + 1e-10f);
        float Dv = 0.5f * (T1[a][b] + T2[b][a]) + b3d + (g1 - g0);
        out[ij] = Dv > 0.f ? 1.f : 0.f;
        if (fabsf(Dv) < FLAG_THRESH) {
            unsigned int idx = atomicAdd(cnt, 1u);
            if (idx < FLAG_CAP) list[idx] = (unsigned int)ij;
        }
    }
}

// ---------------------------------------------------------------------------
// K4: f64 repair. One wave per flagged pair; lane = output o.
// Uses exact f64 pre-activations A64/B64; W2 staged to LDS as f64.
// ---------------------------------------------------------------------------
__global__ __launch_bounds__(256) void repair_kernel(
    const double* __restrict__ A64, const double* __restrict__ B64,
    const float* __restrict__ W2, const float* __restrict__ b2,
    const float* __restrict__ W3, const float* __restrict__ b3,
    const float* __restrict__ u,
    float* __restrict__ out, const unsigned int* __restrict__ cnt,
    const unsigned int* __restrict__ list)
{
    __shared__ double W2d[H1 * H2];     // 64 KB
    __shared__ double h1s[4][2][H1];    // 8 KB
    int tid = threadIdx.x;
    int lane = tid & 63;
    int wave = tid >> 6;

    #pragma unroll
    for (int r = 0; r < 32; ++r) {
        int idx = tid + r * 256;
        W2d[idx] = (double)W2[idx];
    }
    __syncthreads();

    unsigned int n = *cnt;
    if (n > FLAG_CAP) n = FLAG_CAP;
    int gw = blockIdx.x * 4 + wave;
    int TW = gridDim.x * 4;
    int iters = (int)((n + TW - 1) / TW);
    double w3dd = (double)W3[lane * 2 + 1] - (double)W3[lane * 2 + 0];
    double b2d = (double)b2[lane];

    for (int t = 0; t < iters; ++t) {
        int f = gw + t * TW;
        bool active = f < (int)n;
        int ij = active ? (int)list[f] : 0;
        int i = ij >> 10, j = ij & (N - 1);
        if (active) {
            int k0 = lane, k1 = lane + 64;
            double ai0 = A64[(size_t)i * H1 + k0], ai1 = A64[(size_t)i * H1 + k1];
            double aj0 = A64[(size_t)j * H1 + k0], aj1 = A64[(size_t)j * H1 + k1];
            double bi0 = B64[(size_t)i * H1 + k0], bi1 = B64[(size_t)i * H1 + k1];
            double bj0 = B64[(size_t)j * H1 + k0], bj1 = B64[(size_t)j * H1 + k1];
            double v;
            v = ai0 + bj0; h1s[wave][0][k0] = v > 0.0 ? v : 0.0;
            v = ai1 + bj1; h1s[wave][0][k1] = v > 0.0 ? v : 0.0;
            v = aj0 + bi0; h1s[wave][1][k0] = v > 0.0 ? v : 0.0;
            v = aj1 + bi1; h1s[wave][1][k1] = v > 0.0 ? v : 0.0;
        }
        __syncthreads();
        double da = 0.0, db = 0.0;
        {
            double sa = b2d, sb = b2d;
            for (int k = 0; k < H1; ++k) {
                double w = W2d[k * H2 + lane];
                sa += h1s[wave][0][k] * w;
                sb += h1s[wave][1][k] * w;
            }
            if (sa < 0.0) sa = 0.0;
            if (sb < 0.0) sb = 0.0;
            da = sa * w3dd;
            db = sb * w3dd;
        }
        #pragma unroll
        for (int off = 32; off > 0; off >>= 1) {
            da += __shfl_down(da, off, 64);
            db += __shfl_down(db, off, 64);
        }
        if (active && lane == 0) {
            double b3d = (double)b3[1] - (double)b3[0];
            double u0 = (double)u[(((size_t)ij) << 1) + 0];
            double u1 = (double)u[(((size_t)ij) << 1) + 1];
            double g0 = -log(-log(u0 + 1e-10) + 1e-10);
            double g1 = -log(-log(u1 + 1e-10) + 1e-10);
            double Dv = 0.5 * (da + db) + b3d + (g1 - g0);
            out[ij] = Dv > 0.0 ? 1.f : 0.f;
        }
        __syncthreads();
    }
}

// ---------------------------------------------------------------------------
extern "C" void kernel_launch(void* const* d_in, const int* in_sizes, int n_in,
                              void* d_out, int out_size, void* d_ws, size_t ws_size,
                              hipStream_t stream) {
    const float* X  = (const float*)d_in[0];
    const float* W1 = (const float*)d_in[1];
    const float* b1 = (const float*)d_in[2];
    const float* W2 = (const float*)d_in[3];
    const float* b2 = (const float*)d_in[4];
    const float* W3 = (const float*)d_in[5];
    const float* b3 = (const float*)d_in[6];
    const float* u  = (const float*)d_in[7];
    float* out = (float*)d_out;

    // workspace layout (doubles first for alignment)
    double* A64 = (double*)d_ws;                         // 1 MB
    double* B64 = A64 + (size_t)N * H1;                  // 1 MB
    float* dmat = (float*)(B64 + (size_t)N * H1);        // 4 MB
    _Float16* A16 = (_Float16*)(dmat + (size_t)N * N);   // 256 KB
    _Float16* B16 = A16 + (size_t)N * H1;                // 256 KB
    unsigned int* list = (unsigned int*)(B16 + (size_t)N * H1);  // 256 KB
    unsigned int* cnt = list + FLAG_CAP;

    hipMemsetAsync(cnt, 0, sizeof(unsigned int), stream);

    precompute_kernel<<<N, 128, 0, stream>>>(X, W1, b1, A64, B64, A16, B16);
    pair_mlp_kernel<<<(N / 16) * (N / 64), 256, 0, stream>>>(A16, B16, W2, b2, W3, dmat);
    epilogue_kernel<<<(N / 32) * (N / 32), 256, 0, stream>>>(dmat, b3, u, out, cnt, list);
    repair_kernel<<<256, 256, 0, stream>>>(A64, B64, W2, b2, W3, b3, u, out, cnt, list);
}

// Round 3
// 165.032 us; speedup vs baseline: 2.3302x; 1.3300x over previous
//
#include <hip/hip_runtime.h>
#include <hip/hip_bf16.h>

#define N 1024
#define D 64
#define H1 128
#define H2 64
#define FLAG_CAP 65536
#define FLAG_THRESH 0.015f
#define H1PAD 136   // f16 LDS row stride: 272 B = 17*16B (aligned b128, 2-way banks only)

typedef _Float16 half8 __attribute__((ext_vector_type(8)));
typedef float float4v __attribute__((ext_vector_type(4)));

// ---------------------------------------------------------------------------
// K1: pre-activations, exact f64 + f16 copies.
//   A = X @ W1[:64,:] + b1   (1024 x 128)
//   B = X @ W1[64:,:]        (1024 x 128)
// ---------------------------------------------------------------------------
__global__ __launch_bounds__(128) void precompute_kernel(
    const float* __restrict__ X, const float* __restrict__ W1,
    const float* __restrict__ b1,
    double* __restrict__ A64, double* __restrict__ B64,
    _Float16* __restrict__ A16, _Float16* __restrict__ B16)
{
    int i = blockIdx.x;
    int k = threadIdx.x;
    double a = (double)b1[k];
    double b = 0.0;
    for (int c = 0; c < D; ++c) {
        double x = (double)X[i * D + c];              // wave-uniform
        a += x * (double)W1[c * H1 + k];
        b += x * (double)W1[(D + c) * H1 + k];
    }
    A64[i * H1 + k] = a;
    B64[i * H1 + k] = b;
    A16[i * H1 + k] = (_Float16)(float)a;
    B16[i * H1 + k] = (_Float16)(float)b;
}

// ---------------------------------------------------------------------------
// K2: MFMA pair-MLP. Block = 16 i-rows x 64 j-cols = 1024 pairs.
// GEMM: M=16 j's (per tile), K=128 (h = relu(A16[i]+B16[j]) on the fly),
//       N=64 outputs (W2 resident in VGPRs as B-frags), layer-3 fused.
// hb fragments are loaded once per jq and reused across the 4 i-rows.
// ---------------------------------------------------------------------------
__global__ __launch_bounds__(256, 4) void pair_mlp_kernel(
    const _Float16* __restrict__ A16, const _Float16* __restrict__ B16,
    const float* __restrict__ W2, const float* __restrict__ b2,
    const float* __restrict__ W3, float* __restrict__ dmat)
{
    __shared__ _Float16 As16[16 * H1PAD];
    __shared__ _Float16 Bs16[64 * H1PAD];
    __shared__ _Float16 W2t[64 * H1PAD];   // transposed: W2t[n][k]

    int tid = threadIdx.x;
    int it = blockIdx.x >> 4;      // 0..63
    int jt = blockIdx.x & 15;      // 0..15
    int ti = it << 4;              // i0
    int tj = jt << 6;              // j0

    // ---- stage A16 rows (16x128 f16): 8 f16 per thread
    {
        int row = tid >> 4;
        int col = (tid & 15) << 3;
        *(half8*)&As16[row * H1PAD + col] =
            *(const half8*)&A16[(size_t)(ti + row) * H1 + col];
    }
    // ---- stage B16 rows (64x128 f16): 32 f16 per thread
    #pragma unroll
    for (int r = 0; r < 4; ++r) {
        int v = tid + r * 256;
        int row = v >> 4;
        int col = (v & 15) << 3;
        *(half8*)&Bs16[row * H1PAD + col] =
            *(const half8*)&B16[(size_t)(tj + row) * H1 + col];
    }
    // ---- stage W2 transposed to f16: W2t[n][k] = W2[k][n]
    #pragma unroll
    for (int r = 0; r < 32; ++r) {
        int idx = tid + r * 256;   // 0..8191
        int k = idx >> 6;
        int n = idx & 63;
        W2t[n * H1PAD + k] = (_Float16)W2[idx];
    }
    __syncthreads();

    int lane = tid & 63;
    int wave = tid >> 6;
    int quad = lane >> 4;          // 0..3
    int m = lane & 15;             // B-frag n / A-frag m

    // ---- B-frags: W2 fully in registers. bfrag[ks][nt]: k=quad*8+j+32*ks, n=m+16*nt
    half8 bfrag[4][4];
    #pragma unroll
    for (int ks = 0; ks < 4; ++ks)
        #pragma unroll
        for (int nt = 0; nt < 4; ++nt)
            bfrag[ks][nt] = *(const half8*)&W2t[(m + 16 * nt) * H1PAD + quad * 8 + 32 * ks];

    // ---- per-lane epilogue constants: o = m + 16*nt
    float b2f[4], w3df[4];
    #pragma unroll
    for (int nt = 0; nt < 4; ++nt) {
        int o = m + 16 * nt;
        b2f[nt] = b2[o];
        w3df[nt] = W3[o * 2 + 1] - W3[o * 2 + 0];
    }

    const half8 zero8 = {0, 0, 0, 0, 0, 0, 0, 0};

    #pragma unroll 1
    for (int jq = 0; jq < 4; ++jq) {
        int jj0 = jq << 4;
        half8 hb[4];
        #pragma unroll
        for (int ks = 0; ks < 4; ++ks)
            hb[ks] = *(const half8*)&Bs16[(jj0 + m) * H1PAD + quad * 8 + 32 * ks];

        #pragma unroll 1
        for (int i4 = 0; i4 < 4; ++i4) {
            int ii = (wave << 2) + i4;

            float4v acc[4];
            #pragma unroll
            for (int nt = 0; nt < 4; ++nt) {
                float bv = b2f[nt];
                acc[nt] = (float4v){bv, bv, bv, bv};   // fold b2 into C init
            }

            #pragma unroll
            for (int ks = 0; ks < 4; ++ks) {
                half8 ha = *(const half8*)&As16[ii * H1PAD + quad * 8 + 32 * ks]; // broadcast
                half8 h = __builtin_elementwise_max(ha + hb[ks], zero8);          // relu
                #pragma unroll
                for (int nt = 0; nt < 4; ++nt)
                    acc[nt] = __builtin_amdgcn_mfma_f32_16x16x32_f16(h, bfrag[ks][nt], acc[nt], 0, 0, 0);
            }

            // ---- fused layer 3: reduce over o (cols = lane&15 across 4 nt)
            float p[4];
            #pragma unroll
            for (int reg = 0; reg < 4; ++reg) {
                float s = 0.f;
                #pragma unroll
                for (int nt = 0; nt < 4; ++nt)
                    s = fmaf(fmaxf(acc[nt][reg], 0.f), w3df[nt], s);
                p[reg] = s;
            }
            #pragma unroll
            for (int off = 1; off < 16; off <<= 1) {
                #pragma unroll
                for (int reg = 0; reg < 4; ++reg)
                    p[reg] += __shfl_xor(p[reg], off, 64);
            }
            if (m == 0) {
                int row = ti + ii;
                int colb = tj + jj0 + quad * 4;
                #pragma unroll
                for (int reg = 0; reg < 4; ++reg)
                    dmat[(size_t)row * N + colb + reg] = p[reg];
            }
        }
    }
}

// ---------------------------------------------------------------------------
// K3: D = 0.5*(d[i][j]+d[j][i]) + b3d + (g1-g0); out = D > 0; flag |D|<thresh
// Flags aggregated per-block in LDS; ONE global atomic per block.
// ---------------------------------------------------------------------------
__global__ __launch_bounds__(256) void epilogue_kernel(
    const float* __restrict__ dmat, const float* __restrict__ b3,
    const float* __restrict__ u,
    float* __restrict__ out, unsigned int* __restrict__ cnt,
    unsigned int* __restrict__ list)
{
    __shared__ float T1[32][33];
    __shared__ float T2[32][33];
    __shared__ unsigned int lflags[1024];
    __shared__ unsigned int lcnt, lbase;

    int bi = blockIdx.x >> 5;
    int bj = blockIdx.x & 31;
    int i0 = bi * 32, j0 = bj * 32;
    int tid = threadIdx.x;
    int r = tid >> 3;
    int c4 = (tid & 7) << 2;
    if (tid == 0) lcnt = 0;
    *(float4*)&T1[r][c4] = *(const float4*)&dmat[(size_t)(i0 + r) * N + j0 + c4];
    *(float4*)&T2[r][c4] = *(const float4*)&dmat[(size_t)(j0 + r) * N + i0 + c4];
    __syncthreads();

    float b3d = b3[1] - b3[0];
    int a = tid >> 3;
    int b0 = (tid & 7) << 2;
    int ij0 = (i0 + a) * N + (j0 + b0);

    float4 u01 = *(const float4*)&u[((size_t)ij0) * 2];       // j0..j0+1
    float4 u23 = *(const float4*)&u[((size_t)ij0) * 2 + 4];   // j0+2..j0+3
    float uu[8] = {u01.x, u01.y, u01.z, u01.w, u23.x, u23.y, u23.z, u23.w};

    float4 res;
    float* resp = &res.x;
    #pragma unroll
    for (int q = 0; q < 4; ++q) {
        int b = b0 + q;
        float g0 = -logf(-logf(uu[2 * q] + 1e-10f) + 1e-10f);
        float g1 = -logf(-logf(uu[2 * q + 1] + 1e-10f) + 1e-10f);
        float Dv = 0.5f * (T1[a][b] + T2[b][a]) + b3d + (g1 - g0);
        resp[q] = Dv > 0.f ? 1.f : 0.f;
        if (fabsf(Dv) < FLAG_THRESH) {
            unsigned int idx = atomicAdd(&lcnt, 1u);   // LDS atomic (fast)
            lflags[idx] = (unsigned int)(ij0 + q);
        }
    }
    *(float4*)&out[ij0] = res;

    __syncthreads();
    if (tid == 0) lbase = atomicAdd(cnt, lcnt);        // ONE global atomic/block
    __syncthreads();
    unsigned int nl = lcnt, base = lbase;
    for (unsigned int k = tid; k < nl; k += 256) {
        unsigned int g = base + k;
        if (g < FLAG_CAP) list[g] = lflags[k];
    }
}

// ---------------------------------------------------------------------------
// K4: f64 repair. One wave per flagged pair; lane = output o.
// Uses exact f64 pre-activations A64/B64; W2 staged to LDS as f64.
// ---------------------------------------------------------------------------
__global__ __launch_bounds__(256) void repair_kernel(
    const double* __restrict__ A64, const double* __restrict__ B64,
    const float* __restrict__ W2, const float* __restrict__ b2,
    const float* __restrict__ W3, const float* __restrict__ b3,
    const float* __restrict__ u,
    float* __restrict__ out, const unsigned int* __restrict__ cnt,
    const unsigned int* __restrict__ list)
{
    __shared__ double W2d[H1 * H2];     // 64 KB
    __shared__ double h1s[4][2][H1];    // 8 KB
    int tid = threadIdx.x;
    int lane = tid & 63;
    int wave = tid >> 6;

    #pragma unroll
    for (int r = 0; r < 32; ++r) {
        int idx = tid + r * 256;
        W2d[idx] = (double)W2[idx];
    }
    __syncthreads();

    unsigned int n = *cnt;
    if (n > FLAG_CAP) n = FLAG_CAP;
    int gw = blockIdx.x * 4 + wave;
    int TW = gridDim.x * 4;
    int iters = (int)((n + TW - 1) / TW);
    double w3dd = (double)W3[lane * 2 + 1] - (double)W3[lane * 2 + 0];
    double b2d = (double)b2[lane];

    for (int t = 0; t < iters; ++t) {
        int f = gw + t * TW;
        bool active = f < (int)n;
        int ij = active ? (int)list[f] : 0;
        int i = ij >> 10, j = ij & (N - 1);
        if (active) {
            int k0 = lane, k1 = lane + 64;
            double ai0 = A64[(size_t)i * H1 + k0], ai1 = A64[(size_t)i * H1 + k1];
            double aj0 = A64[(size_t)j * H1 + k0], aj1 = A64[(size_t)j * H1 + k1];
            double bi0 = B64[(size_t)i * H1 + k0], bi1 = B64[(size_t)i * H1 + k1];
            double bj0 = B64[(size_t)j * H1 + k0], bj1 = B64[(size_t)j * H1 + k1];
            double v;
            v = ai0 + bj0; h1s[wave][0][k0] = v > 0.0 ? v : 0.0;
            v = ai1 + bj1; h1s[wave][0][k1] = v > 0.0 ? v : 0.0;
            v = aj0 + bi0; h1s[wave][1][k0] = v > 0.0 ? v : 0.0;
            v = aj1 + bi1; h1s[wave][1][k1] = v > 0.0 ? v : 0.0;
        }
        __syncthreads();
        double da = 0.0, db = 0.0;
        {
            double sa = b2d, sb = b2d;
            for (int k = 0; k < H1; ++k) {
                double w = W2d[k * H2 + lane];
                sa += h1s[wave][0][k] * w;
                sb += h1s[wave][1][k] * w;
            }
            if (sa < 0.0) sa = 0.0;
            if (sb < 0.0) sb = 0.0;
            da = sa * w3dd;
            db = sb * w3dd;
        }
        #pragma unroll
        for (int off = 32; off > 0; off >>= 1) {
            da += __shfl_down(da, off, 64);
            db += __shfl_down(db, off, 64);
        }
        if (active && lane == 0) {
            double b3dd = (double)b3[1] - (double)b3[0];
            double u0 = (double)u[(((size_t)ij) << 1) + 0];
            double u1 = (double)u[(((size_t)ij) << 1) + 1];
            double g0 = -log(-log(u0 + 1e-10) + 1e-10);
            double g1 = -log(-log(u1 + 1e-10) + 1e-10);
            double Dv = 0.5 * (da + db) + b3dd + (g1 - g0);
            out[ij] = Dv > 0.0 ? 1.f : 0.f;
        }
        __syncthreads();
    }
}

// ---------------------------------------------------------------------------
extern "C" void kernel_launch(void* const* d_in, const int* in_sizes, int n_in,
                              void* d_out, int out_size, void* d_ws, size_t ws_size,
                              hipStream_t stream) {
    const float* X  = (const float*)d_in[0];
    const float* W1 = (const float*)d_in[1];
    const float* b1 = (const float*)d_in[2];
    const float* W2 = (const float*)d_in[3];
    const float* b2 = (const float*)d_in[4];
    const float* W3 = (const float*)d_in[5];
    const float* b3 = (const float*)d_in[6];
    const float* u  = (const float*)d_in[7];
    float* out = (float*)d_out;

    // workspace layout (doubles first for alignment)
    double* A64 = (double*)d_ws;                         // 1 MB
    double* B64 = A64 + (size_t)N * H1;                  // 1 MB
    float* dmat = (float*)(B64 + (size_t)N * H1);        // 4 MB
    _Float16* A16 = (_Float16*)(dmat + (size_t)N * N);   // 256 KB
    _Float16* B16 = A16 + (size_t)N * H1;                // 256 KB
    unsigned int* list = (unsigned int*)(B16 + (size_t)N * H1);  // 256 KB
    unsigned int* cnt = list + FLAG_CAP;

    hipMemsetAsync(cnt, 0, sizeof(unsigned int), stream);

    precompute_kernel<<<N, 128, 0, stream>>>(X, W1, b1, A64, B64, A16, B16);
    pair_mlp_kernel<<<(N / 16) * (N / 64), 256, 0, stream>>>(A16, B16, W2, b2, W3, dmat);
    epilogue_kernel<<<(N / 32) * (N / 32), 256, 0, stream>>>(dmat, b3, u, out, cnt, list);
    repair_kernel<<<256, 256, 0, stream>>>(A64, B64, W2, b2, W3, b3, u, out, cnt, list);
}

// Round 5
// 152.430 us; speedup vs baseline: 2.5229x; 1.0827x over previous
//
#include <hip/hip_runtime.h>
#include <hip/hip_bf16.h>

#define N 1024
#define D 64
#define H1 128
#define H2 64
#define FLAG_CAP 65536
#define FLAG_THRESH 0.015f
#define H1PAD 136   // f16 LDS row stride: 272 B = 17*16B (aligned b128, 2-way banks only)

typedef _Float16 half8 __attribute__((ext_vector_type(8)));
typedef float float4v __attribute__((ext_vector_type(4)));

// DPP row_shr reduction step: lane i += lane (i - SH) within its 16-lane row
// (0 shifted in). Pure VALU pipe. Row TOTAL accumulates at lane 15 of the row.
template <int CTRL>
__device__ __forceinline__ float dpp_add_f32(float x) {
    int s = __builtin_amdgcn_update_dpp(0, __builtin_bit_cast(int, x),
                                        CTRL, 0xF, 0xF, true);
    return x + __builtin_bit_cast(float, s);
}

// ---------------------------------------------------------------------------
// K1: pre-activations, exact f64 + f16 copies. Also zeroes the flag counter.
//   A = X @ W1[:64,:] + b1   (1024 x 128)
//   B = X @ W1[64:,:]        (1024 x 128)
// ---------------------------------------------------------------------------
__global__ __launch_bounds__(128) void precompute_kernel(
    const float* __restrict__ X, const float* __restrict__ W1,
    const float* __restrict__ b1,
    double* __restrict__ A64, double* __restrict__ B64,
    _Float16* __restrict__ A16, _Float16* __restrict__ B16,
    unsigned int* __restrict__ cnt)
{
    if (blockIdx.x == 0 && threadIdx.x == 0) *cnt = 0;  // visible at next kernel boundary
    int i = blockIdx.x;
    int k = threadIdx.x;
    double a = (double)b1[k];
    double b = 0.0;
    for (int c = 0; c < D; ++c) {
        double x = (double)X[i * D + c];              // wave-uniform
        a += x * (double)W1[c * H1 + k];
        b += x * (double)W1[(D + c) * H1 + k];
    }
    A64[i * H1 + k] = a;
    B64[i * H1 + k] = b;
    A16[i * H1 + k] = (_Float16)(float)a;
    B16[i * H1 + k] = (_Float16)(float)b;
}

// ---------------------------------------------------------------------------
// K2: MFMA pair-MLP. Block = 16 i-rows x 64 j-cols = 1024 pairs.
// GEMM: M=16 pairs (fixed i, 16 j's), K=128 (h = relu(A16[i]+B16[j]) on the
// fly), N=64 outputs (W2 resident in VGPRs), layer-3 fused via DPP reduce.
// ---------------------------------------------------------------------------
__global__ __launch_bounds__(256, 4) void pair_mlp_kernel(
    const _Float16* __restrict__ A16, const _Float16* __restrict__ B16,
    const float* __restrict__ W2, const float* __restrict__ b2,
    const float* __restrict__ W3, float* __restrict__ dmat)
{
    __shared__ _Float16 As16[16 * H1PAD];
    __shared__ _Float16 Bs16[64 * H1PAD];
    __shared__ _Float16 W2t[64 * H1PAD];   // transposed: W2t[n][k]

    int tid = threadIdx.x;
    int it = blockIdx.x >> 4;      // 0..63
    int jt = blockIdx.x & 15;      // 0..15
    int ti = it << 4;              // i0
    int tj = jt << 6;              // j0

    // ---- stage A16 rows (16x128 f16): 8 f16 per thread
    {
        int row = tid >> 4;
        int col = (tid & 15) << 3;
        *(half8*)&As16[row * H1PAD + col] =
            *(const half8*)&A16[(size_t)(ti + row) * H1 + col];
    }
    // ---- stage B16 rows (64x128 f16): 32 f16 per thread
    #pragma unroll
    for (int r = 0; r < 4; ++r) {
        int v = tid + r * 256;
        int row = v >> 4;
        int col = (v & 15) << 3;
        *(half8*)&Bs16[row * H1PAD + col] =
            *(const half8*)&B16[(size_t)(tj + row) * H1 + col];
    }
    // ---- stage W2 transposed to f16: W2t[n][k] = W2[k][n]
    #pragma unroll
    for (int r = 0; r < 32; ++r) {
        int idx = tid + r * 256;   // 0..8191
        int k = idx >> 6;
        int n = idx & 63;
        W2t[n * H1PAD + k] = (_Float16)W2[idx];
    }
    __syncthreads();

    int lane = tid & 63;
    int wave = tid >> 6;
    int quad = lane >> 4;          // 0..3
    int m = lane & 15;             // B-frag n / A-frag m

    // ---- B-frags: W2 fully in registers. bfrag[ks][nt]: k=quad*8+j+32*ks, n=m+16*nt
    half8 bfrag[4][4];
    #pragma unroll
    for (int ks = 0; ks < 4; ++ks)
        #pragma unroll
        for (int nt = 0; nt < 4; ++nt)
            bfrag[ks][nt] = *(const half8*)&W2t[(m + 16 * nt) * H1PAD + quad * 8 + 32 * ks];

    // ---- per-lane epilogue constants: o = m + 16*nt
    float b2f[4], w3df[4];
    #pragma unroll
    for (int nt = 0; nt < 4; ++nt) {
        int o = m + 16 * nt;
        b2f[nt] = b2[o];
        w3df[nt] = W3[o * 2 + 1] - W3[o * 2 + 0];
    }

    const half8 zero8 = {0, 0, 0, 0, 0, 0, 0, 0};

    #pragma unroll 1
    for (int jq = 0; jq < 4; ++jq) {
        int jj0 = jq << 4;
        half8 hb[4];
        #pragma unroll
        for (int ks = 0; ks < 4; ++ks)
            hb[ks] = *(const half8*)&Bs16[(jj0 + m) * H1PAD + quad * 8 + 32 * ks];

        #pragma unroll 1
        for (int i4 = 0; i4 < 4; ++i4) {
            int ii = (wave << 2) + i4;

            float4v acc[4];
            #pragma unroll
            for (int nt = 0; nt < 4; ++nt) {
                float bv = b2f[nt];
                acc[nt] = (float4v){bv, bv, bv, bv};   // fold b2 into C init
            }

            #pragma unroll
            for (int ks = 0; ks < 4; ++ks) {
                half8 ha = *(const half8*)&As16[ii * H1PAD + quad * 8 + 32 * ks]; // broadcast
                half8 h = __builtin_elementwise_max(ha + hb[ks], zero8);          // relu
                #pragma unroll
                for (int nt = 0; nt < 4; ++nt)
                    acc[nt] = __builtin_amdgcn_mfma_f32_16x16x32_f16(h, bfrag[ks][nt], acc[nt], 0, 0, 0);
            }

            // ---- fused layer 3: per-lane fold over nt, then DPP row-reduce over m.
            // row_shr accumulates toward HIGHER lanes: total lands at m==15.
            float p[4];
            #pragma unroll
            for (int reg = 0; reg < 4; ++reg) {
                float s = 0.f;
                #pragma unroll
                for (int nt = 0; nt < 4; ++nt)
                    s = fmaf(fmaxf(acc[nt][reg], 0.f), w3df[nt], s);
                s = dpp_add_f32<0x118>(s);   // row_shr:8
                s = dpp_add_f32<0x114>(s);   // row_shr:4
                s = dpp_add_f32<0x112>(s);   // row_shr:2
                s = dpp_add_f32<0x111>(s);   // row_shr:1
                p[reg] = s;                  // row total valid at m==15
            }
            if (m == 15) {
                int row = ti + ii;
                int colb = tj + jj0 + quad * 4;
                float4 st = {p[0], p[1], p[2], p[3]};
                *(float4*)&dmat[(size_t)row * N + colb] = st;   // 16B-aligned
            }
        }
    }
}

// ---------------------------------------------------------------------------
// K3: D = 0.5*(d[i][j]+d[j][i]) + b3d + (g1-g0); out = D > 0; flag |D|<thresh
// Flags aggregated per-block in LDS; ONE global atomic per block.
// ---------------------------------------------------------------------------
__global__ __launch_bounds__(256) void epilogue_kernel(
    const float* __restrict__ dmat, const float* __restrict__ b3,
    const float* __restrict__ u,
    float* __restrict__ out, unsigned int* __restrict__ cnt,
    unsigned int* __restrict__ list)
{
    __shared__ float T1[32][33];
    __shared__ float T2[32][33];
    __shared__ unsigned int lflags[1024];
    __shared__ unsigned int lcnt, lbase;

    int bi = blockIdx.x >> 5;
    int bj = blockIdx.x & 31;
    int i0 = bi * 32, j0 = bj * 32;
    int tid = threadIdx.x;
    int r = tid >> 3;
    int c4 = (tid & 7) << 2;
    if (tid == 0) lcnt = 0;
    *(float4*)&T1[r][c4] = *(const float4*)&dmat[(size_t)(i0 + r) * N + j0 + c4];
    *(float4*)&T2[r][c4] = *(const float4*)&dmat[(size_t)(j0 + r) * N + i0 + c4];
    __syncthreads();

    float b3d = b3[1] - b3[0];
    int a = tid >> 3;
    int b0 = (tid & 7) << 2;
    int ij0 = (i0 + a) * N + (j0 + b0);

    float4 u01 = *(const float4*)&u[((size_t)ij0) * 2];       // j0..j0+1
    float4 u23 = *(const float4*)&u[((size_t)ij0) * 2 + 4];   // j0+2..j0+3
    float uu[8] = {u01.x, u01.y, u01.z, u01.w, u23.x, u23.y, u23.z, u23.w};

    float4 res;
    float* resp = &res.x;
    #pragma unroll
    for (int q = 0; q < 4; ++q) {
        int b = b0 + q;
        float g0 = -logf(-logf(uu[2 * q] + 1e-10f) + 1e-10f);
        float g1 = -logf(-logf(uu[2 * q + 1] + 1e-10f) + 1e-10f);
        float Dv = 0.5f * (T1[a][b] + T2[b][a]) + b3d + (g1 - g0);
        resp[q] = Dv > 0.f ? 1.f : 0.f;
        if (fabsf(Dv) < FLAG_THRESH) {
            unsigned int idx = atomicAdd(&lcnt, 1u);   // LDS atomic (fast)
            lflags[idx] = (unsigned int)(ij0 + q);
        }
    }
    *(float4*)&out[ij0] = res;

    __syncthreads();
    if (tid == 0) lbase = atomicAdd(cnt, lcnt);        // ONE global atomic/block
    __syncthreads();
    unsigned int nl = lcnt, base = lbase;
    for (unsigned int k = tid; k < nl; k += 256) {
        unsigned int g = base + k;
        if (g < FLAG_CAP) list[g] = lflags[k];
    }
}

// ---------------------------------------------------------------------------
// K4: f64 repair. ONE WAVE per block, 2048 blocks. No W2 LDS stage (global
// reads are coalesced and L1/L2-resident). lane = output o in the k-loop.
// ---------------------------------------------------------------------------
__global__ __launch_bounds__(64) void repair_kernel(
    const double* __restrict__ A64, const double* __restrict__ B64,
    const float* __restrict__ W2, const float* __restrict__ b2,
    const float* __restrict__ W3, const float* __restrict__ b3,
    const float* __restrict__ u,
    float* __restrict__ out, const unsigned int* __restrict__ cnt,
    const unsigned int* __restrict__ list)
{
    __shared__ double h1s[2][H1];   // 2 KB
    int lane = threadIdx.x;

    unsigned int n = *cnt;
    if (n > FLAG_CAP) n = FLAG_CAP;
    double w3dd = (double)W3[lane * 2 + 1] - (double)W3[lane * 2 + 0];
    double b2d = (double)b2[lane];

    for (unsigned int f = blockIdx.x; f < n; f += gridDim.x) {
        int ij = (int)list[f];
        int i = ij >> 10, j = ij & (N - 1);
        {   // phase 1: lane = k (two k's per lane), coalesced f64 loads
            int k0 = lane, k1 = lane + 64;
            double ai0 = A64[(size_t)i * H1 + k0], ai1 = A64[(size_t)i * H1 + k1];
            double aj0 = A64[(size_t)j * H1 + k0], aj1 = A64[(size_t)j * H1 + k1];
            double bi0 = B64[(size_t)i * H1 + k0], bi1 = B64[(size_t)i * H1 + k1];
            double bj0 = B64[(size_t)j * H1 + k0], bj1 = B64[(size_t)j * H1 + k1];
            double v;
            v = ai0 + bj0; h1s[0][k0] = v > 0.0 ? v : 0.0;
            v = ai1 + bj1; h1s[0][k1] = v > 0.0 ? v : 0.0;
            v = aj0 + bi0; h1s[1][k0] = v > 0.0 ? v : 0.0;
            v = aj1 + bi1; h1s[1][k1] = v > 0.0 ? v : 0.0;
        }
        __syncthreads();   // single-wave block: cheap
        double sa = b2d, sb = b2d;
        #pragma unroll 4
        for (int k = 0; k < H1; ++k) {
            double w = (double)W2[k * H2 + lane];   // coalesced, L1-resident
            sa += h1s[0][k] * w;
            sb += h1s[1][k] * w;
        }
        if (sa < 0.0) sa = 0.0;
        if (sb < 0.0) sb = 0.0;
        double da = sa * w3dd;
        double db = sb * w3dd;
        #pragma unroll
        for (int off = 32; off > 0; off >>= 1) {
            da += __shfl_down(da, off, 64);
            db += __shfl_down(db, off, 64);
        }
        if (lane == 0) {
            double b3dd = (double)b3[1] - (double)b3[0];
            double u0 = (double)u[(((size_t)ij) << 1) + 0];
            double u1 = (double)u[(((size_t)ij) << 1) + 1];
            double g0 = -log(-log(u0 + 1e-10) + 1e-10);
            double g1 = -log(-log(u1 + 1e-10) + 1e-10);
            double Dv = 0.5 * (da + db) + b3dd + (g1 - g0);
            out[ij] = Dv > 0.0 ? 1.f : 0.f;
        }
        __syncthreads();   // h1s reuse guard
    }
}

// ---------------------------------------------------------------------------
extern "C" void kernel_launch(void* const* d_in, const int* in_sizes, int n_in,
                              void* d_out, int out_size, void* d_ws, size_t ws_size,
                              hipStream_t stream) {
    const float* X  = (const float*)d_in[0];
    const float* W1 = (const float*)d_in[1];
    const float* b1 = (const float*)d_in[2];
    const float* W2 = (const float*)d_in[3];
    const float* b2 = (const float*)d_in[4];
    const float* W3 = (const float*)d_in[5];
    const float* b3 = (const float*)d_in[6];
    const float* u  = (const float*)d_in[7];
    float* out = (float*)d_out;

    // workspace layout (doubles first for alignment)
    double* A64 = (double*)d_ws;                         // 1 MB
    double* B64 = A64 + (size_t)N * H1;                  // 1 MB
    float* dmat = (float*)(B64 + (size_t)N * H1);        // 4 MB
    _Float16* A16 = (_Float16*)(dmat + (size_t)N * N);   // 256 KB
    _Float16* B16 = A16 + (size_t)N * H1;                // 256 KB
    unsigned int* list = (unsigned int*)(B16 + (size_t)N * H1);  // 256 KB
    unsigned int* cnt = list + FLAG_CAP;

    precompute_kernel<<<N, 128, 0, stream>>>(X, W1, b1, A64, B64, A16, B16, cnt);
    pair_mlp_kernel<<<(N / 16) * (N / 64), 256, 0, stream>>>(A16, B16, W2, b2, W3, dmat);
    epilogue_kernel<<<(N / 32) * (N / 32), 256, 0, stream>>>(dmat, b3, u, out, cnt, list);
    repair_kernel<<<2048, 64, 0, stream>>>(A64, B64, W2, b2, W3, b3, u, out, cnt, list);
}

// Round 6
// 147.144 us; speedup vs baseline: 2.6135x; 1.0359x over previous
//
#include <hip/hip_runtime.h>
#include <hip/hip_bf16.h>

#define N 1024
#define D 64
#define H1 128
#define H2 64
#define FLAG_CAP 65536
#define FLAG_THRESH 0.015f
#define H1PAD 136   // f16 LDS row stride: 272 B = 17*16B (aligned b128, 2-way banks only)

typedef _Float16 half8 __attribute__((ext_vector_type(8)));
typedef float float4v __attribute__((ext_vector_type(4)));

// ---------------------------------------------------------------------------
// K1: pre-activations, exact f64 + f16 copies. Also zeroes the flag counter.
//   A = X @ W1[:64,:] + b1   (1024 x 128)
//   B = X @ W1[64:,:]        (1024 x 128)
// ---------------------------------------------------------------------------
__global__ __launch_bounds__(128) void precompute_kernel(
    const float* __restrict__ X, const float* __restrict__ W1,
    const float* __restrict__ b1,
    double* __restrict__ A64, double* __restrict__ B64,
    _Float16* __restrict__ A16, _Float16* __restrict__ B16,
    unsigned int* __restrict__ cnt)
{
    if (blockIdx.x == 0 && threadIdx.x == 0) *cnt = 0;  // visible at next kernel boundary
    int i = blockIdx.x;
    int k = threadIdx.x;
    double a = (double)b1[k];
    double b = 0.0;
    for (int c = 0; c < D; ++c) {
        double x = (double)X[i * D + c];              // wave-uniform
        a += x * (double)W1[c * H1 + k];
        b += x * (double)W1[(D + c) * H1 + k];
    }
    A64[i * H1 + k] = a;
    B64[i * H1 + k] = b;
    A16[i * H1 + k] = (_Float16)(float)a;
    B16[i * H1 + k] = (_Float16)(float)b;
}

// ---------------------------------------------------------------------------
// K2: MFMA pair-MLP. Block = 16 i-rows x 64 j-cols = 1024 pairs.
// OPERAND-SWAPPED GEMM: A = W2 (rows = o), B = h = relu(A16[i]+B16[j])
// (cols = pairs). D[row=o_local][col=pair]: each lane (pair = lane&15) holds
// S for o = quad*4+reg+16*nt -> layer-3 reduce is IN-LANE + 2 shfl_xor.
// ---------------------------------------------------------------------------
__global__ __launch_bounds__(256, 3) void pair_mlp_kernel(
    const _Float16* __restrict__ A16, const _Float16* __restrict__ B16,
    const float* __restrict__ W2, const float* __restrict__ b2,
    const float* __restrict__ W3, float* __restrict__ dmat)
{
    __shared__ _Float16 As16[16 * H1PAD];
    __shared__ _Float16 Bs16[64 * H1PAD];
    __shared__ _Float16 W2t[64 * H1PAD];   // transposed: W2t[n][k]

    int tid = threadIdx.x;
    int it = blockIdx.x >> 4;      // 0..63
    int jt = blockIdx.x & 15;      // 0..15
    int ti = it << 4;              // i0
    int tj = jt << 6;              // j0

    // ---- stage A16 rows (16x128 f16): 8 f16 per thread
    {
        int row = tid >> 4;
        int col = (tid & 15) << 3;
        *(half8*)&As16[row * H1PAD + col] =
            *(const half8*)&A16[(size_t)(ti + row) * H1 + col];
    }
    // ---- stage B16 rows (64x128 f16): 32 f16 per thread
    #pragma unroll
    for (int r = 0; r < 4; ++r) {
        int v = tid + r * 256;
        int row = v >> 4;
        int col = (v & 15) << 3;
        *(half8*)&Bs16[row * H1PAD + col] =
            *(const half8*)&B16[(size_t)(tj + row) * H1 + col];
    }
    // ---- stage W2 transposed to f16: W2t[n][k] = W2[k][n]
    #pragma unroll
    for (int r = 0; r < 32; ++r) {
        int idx = tid + r * 256;   // 0..8191
        int k = idx >> 6;
        int n = idx & 63;
        W2t[n * H1PAD + k] = (_Float16)W2[idx];
    }
    __syncthreads();

    int lane = tid & 63;
    int wave = tid >> 6;
    int quad = lane >> 4;          // 0..3
    int m = lane & 15;             // A-frag row (o_local) AND B-frag col (pair)

    // ---- A-frags: W2 fully in registers. afrag[ks][nt]: A[m][k] = W2[k][m+16nt]
    half8 afrag[4][4];
    #pragma unroll
    for (int ks = 0; ks < 4; ++ks)
        #pragma unroll
        for (int nt = 0; nt < 4; ++nt)
            afrag[ks][nt] = *(const half8*)&W2t[(m + 16 * nt) * H1PAD + quad * 8 + 32 * ks];

    // ---- per-lane epilogue constants: this lane's o for (nt,reg) = quad*4+reg+16*nt
    float b2x[4][4], w3x[4][4];
    #pragma unroll
    for (int nt = 0; nt < 4; ++nt)
        #pragma unroll
        for (int reg = 0; reg < 4; ++reg) {
            int o = (quad << 2) + reg + (nt << 4);
            b2x[nt][reg] = b2[o];
            w3x[nt][reg] = W3[o * 2 + 1] - W3[o * 2 + 0];
        }

    const half8 zero8 = {0, 0, 0, 0, 0, 0, 0, 0};

    #pragma unroll 1
    for (int jq = 0; jq < 4; ++jq) {
        int jj0 = jq << 4;
        half8 hb[4];               // this lane's pair j = tj + jj0 + m
        #pragma unroll
        for (int ks = 0; ks < 4; ++ks)
            hb[ks] = *(const half8*)&Bs16[(jj0 + m) * H1PAD + quad * 8 + 32 * ks];

        #pragma unroll 1
        for (int i4 = 0; i4 < 4; ++i4) {
            int ii = (wave << 2) + i4;

            float4v acc[4];
            #pragma unroll
            for (int nt = 0; nt < 4; ++nt)
                acc[nt] = (float4v){b2x[nt][0], b2x[nt][1], b2x[nt][2], b2x[nt][3]};

            #pragma unroll
            for (int ks = 0; ks < 4; ++ks) {
                half8 ha = *(const half8*)&As16[ii * H1PAD + quad * 8 + 32 * ks]; // broadcast
                half8 h = __builtin_elementwise_max(ha + hb[ks], zero8);          // relu
                #pragma unroll
                for (int nt = 0; nt < 4; ++nt)
                    acc[nt] = __builtin_amdgcn_mfma_f32_16x16x32_f16(afrag[ks][nt], h, acc[nt], 0, 0, 0);
            }

            // ---- fused layer 3: in-lane over 16 o's, then quad-sum via shfl_xor
            float s = 0.f;
            #pragma unroll
            for (int nt = 0; nt < 4; ++nt)
                #pragma unroll
                for (int reg = 0; reg < 4; ++reg)
                    s = fmaf(fmaxf(acc[nt][reg], 0.f), w3x[nt][reg], s);
            s += __shfl_xor(s, 16, 64);
            s += __shfl_xor(s, 32, 64);
            if (quad == 0) {
                // 16 lanes store 16 consecutive floats (coalesced 64 B)
                dmat[(size_t)(ti + ii) * N + (tj + jj0 + m)] = s;
            }
        }
    }
}

// ---------------------------------------------------------------------------
// K3: D = 0.5*(d[i][j]+d[j][i]) + b3d + (g1-g0); out = D > 0; flag |D|<thresh
// Flags aggregated per-block in LDS; ONE global atomic per block.
// ---------------------------------------------------------------------------
__global__ __launch_bounds__(256) void epilogue_kernel(
    const float* __restrict__ dmat, const float* __restrict__ b3,
    const float* __restrict__ u,
    float* __restrict__ out, unsigned int* __restrict__ cnt,
    unsigned int* __restrict__ list)
{
    __shared__ float T1[32][33];
    __shared__ float T2[32][33];
    __shared__ unsigned int lflags[1024];
    __shared__ unsigned int lcnt, lbase;

    int bi = blockIdx.x >> 5;
    int bj = blockIdx.x & 31;
    int i0 = bi * 32, j0 = bj * 32;
    int tid = threadIdx.x;
    int r = tid >> 3;
    int c4 = (tid & 7) << 2;
    if (tid == 0) lcnt = 0;
    *(float4*)&T1[r][c4] = *(const float4*)&dmat[(size_t)(i0 + r) * N + j0 + c4];
    *(float4*)&T2[r][c4] = *(const float4*)&dmat[(size_t)(j0 + r) * N + i0 + c4];
    __syncthreads();

    float b3d = b3[1] - b3[0];
    int a = tid >> 3;
    int b0 = (tid & 7) << 2;
    int ij0 = (i0 + a) * N + (j0 + b0);

    float4 u01 = *(const float4*)&u[((size_t)ij0) * 2];       // j0..j0+1
    float4 u23 = *(const float4*)&u[((size_t)ij0) * 2 + 4];   // j0+2..j0+3
    float uu[8] = {u01.x, u01.y, u01.z, u01.w, u23.x, u23.y, u23.z, u23.w};

    float4 res;
    float* resp = &res.x;
    #pragma unroll
    for (int q = 0; q < 4; ++q) {
        int b = b0 + q;
        float g0 = -logf(-logf(uu[2 * q] + 1e-10f) + 1e-10f);
        float g1 = -logf(-logf(uu[2 * q + 1] + 1e-10f) + 1e-10f);
        float Dv = 0.5f * (T1[a][b] + T2[b][a]) + b3d + (g1 - g0);
        resp[q] = Dv > 0.f ? 1.f : 0.f;
        if (fabsf(Dv) < FLAG_THRESH) {
            unsigned int idx = atomicAdd(&lcnt, 1u);   // LDS atomic (fast)
            lflags[idx] = (unsigned int)(ij0 + q);
        }
    }
    *(float4*)&out[ij0] = res;

    __syncthreads();
    if (tid == 0) lbase = atomicAdd(cnt, lcnt);        // ONE global atomic/block
    __syncthreads();
    unsigned int nl = lcnt, base = lbase;
    for (unsigned int k = tid; k < nl; k += 256) {
        unsigned int g = base + k;
        if (g < FLAG_CAP) list[g] = lflags[k];
    }
}

// ---------------------------------------------------------------------------
// K4: f64 repair. ONE WAVE per block, 2048 blocks. No W2 LDS stage (global
// reads are coalesced and L1/L2-resident). lane = output o in the k-loop.
// ---------------------------------------------------------------------------
__global__ __launch_bounds__(64) void repair_kernel(
    const double* __restrict__ A64, const double* __restrict__ B64,
    const float* __restrict__ W2, const float* __restrict__ b2,
    const float* __restrict__ W3, const float* __restrict__ b3,
    const float* __restrict__ u,
    float* __restrict__ out, const unsigned int* __restrict__ cnt,
    const unsigned int* __restrict__ list)
{
    __shared__ double h1s[2][H1];   // 2 KB
    int lane = threadIdx.x;

    unsigned int n = *cnt;
    if (n > FLAG_CAP) n = FLAG_CAP;
    double w3dd = (double)W3[lane * 2 + 1] - (double)W3[lane * 2 + 0];
    double b2d = (double)b2[lane];

    for (unsigned int f = blockIdx.x; f < n; f += gridDim.x) {
        int ij = (int)list[f];
        int i = ij >> 10, j = ij & (N - 1);
        {   // phase 1: lane = k (two k's per lane), coalesced f64 loads
            int k0 = lane, k1 = lane + 64;
            double ai0 = A64[(size_t)i * H1 + k0], ai1 = A64[(size_t)i * H1 + k1];
            double aj0 = A64[(size_t)j * H1 + k0], aj1 = A64[(size_t)j * H1 + k1];
            double bi0 = B64[(size_t)i * H1 + k0], bi1 = B64[(size_t)i * H1 + k1];
            double bj0 = B64[(size_t)j * H1 + k0], bj1 = B64[(size_t)j * H1 + k1];
            double v;
            v = ai0 + bj0; h1s[0][k0] = v > 0.0 ? v : 0.0;
            v = ai1 + bj1; h1s[0][k1] = v > 0.0 ? v : 0.0;
            v = aj0 + bi0; h1s[1][k0] = v > 0.0 ? v : 0.0;
            v = aj1 + bi1; h1s[1][k1] = v > 0.0 ? v : 0.0;
        }
        __syncthreads();   // single-wave block: cheap
        double sa = b2d, sb = b2d;
        #pragma unroll 4
        for (int k = 0; k < H1; ++k) {
            double w = (double)W2[k * H2 + lane];   // coalesced, L1-resident
            sa += h1s[0][k] * w;
            sb += h1s[1][k] * w;
        }
        if (sa < 0.0) sa = 0.0;
        if (sb < 0.0) sb = 0.0;
        double da = sa * w3dd;
        double db = sb * w3dd;
        #pragma unroll
        for (int off = 32; off > 0; off >>= 1) {
            da += __shfl_down(da, off, 64);
            db += __shfl_down(db, off, 64);
        }
        if (lane == 0) {
            double b3dd = (double)b3[1] - (double)b3[0];
            double u0 = (double)u[(((size_t)ij) << 1) + 0];
            double u1 = (double)u[(((size_t)ij) << 1) + 1];
            double g0 = -log(-log(u0 + 1e-10) + 1e-10);
            double g1 = -log(-log(u1 + 1e-10) + 1e-10);
            double Dv = 0.5 * (da + db) + b3dd + (g1 - g0);
            out[ij] = Dv > 0.0 ? 1.f : 0.f;
        }
        __syncthreads();   // h1s reuse guard
    }
}

// ---------------------------------------------------------------------------
extern "C" void kernel_launch(void* const* d_in, const int* in_sizes, int n_in,
                              void* d_out, int out_size, void* d_ws, size_t ws_size,
                              hipStream_t stream) {
    const float* X  = (const float*)d_in[0];
    const float* W1 = (const float*)d_in[1];
    const float* b1 = (const float*)d_in[2];
    const float* W2 = (const float*)d_in[3];
    const float* b2 = (const float*)d_in[4];
    const float* W3 = (const float*)d_in[5];
    const float* b3 = (const float*)d_in[6];
    const float* u  = (const float*)d_in[7];
    float* out = (float*)d_out;

    // workspace layout (doubles first for alignment)
    double* A64 = (double*)d_ws;                         // 1 MB
    double* B64 = A64 + (size_t)N * H1;                  // 1 MB
    float* dmat = (float*)(B64 + (size_t)N * H1);        // 4 MB
    _Float16* A16 = (_Float16*)(dmat + (size_t)N * N);   // 256 KB
    _Float16* B16 = A16 + (size_t)N * H1;                // 256 KB
    unsigned int* list = (unsigned int*)(B16 + (size_t)N * H1);  // 256 KB
    unsigned int* cnt = list + FLAG_CAP;

    precompute_kernel<<<N, 128, 0, stream>>>(X, W1, b1, A64, B64, A16, B16, cnt);
    pair_mlp_kernel<<<(N / 16) * (N / 64), 256, 0, stream>>>(A16, B16, W2, b2, W3, dmat);
    epilogue_kernel<<<(N / 32) * (N / 32), 256, 0, stream>>>(dmat, b3, u, out, cnt, list);
    repair_kernel<<<2048, 64, 0, stream>>>(A64, B64, W2, b2, W3, b3, u, out, cnt, list);
}

// Round 7
// 142.531 us; speedup vs baseline: 2.6981x; 1.0324x over previous
//
#include <hip/hip_runtime.h>
#include <hip/hip_bf16.h>

#define N 1024
#define D 64
#define H1 128
#define H2 64
#define FLAG_THRESH 0.015f
#define H1PAD 136   // f16 LDS row stride: 272 B = 17*16B (aligned b128, 2-way banks only)

typedef _Float16 half8 __attribute__((ext_vector_type(8)));
typedef float float4v __attribute__((ext_vector_type(4)));

// ---------------------------------------------------------------------------
// K1: pre-activations, exact f64 + f16 copies.
//   A = X @ W1[:64,:] + b1   (1024 x 128)
//   B = X @ W1[64:,:]        (1024 x 128)
// ---------------------------------------------------------------------------
__global__ __launch_bounds__(128) void precompute_kernel(
    const float* __restrict__ X, const float* __restrict__ W1,
    const float* __restrict__ b1,
    double* __restrict__ A64, double* __restrict__ B64,
    _Float16* __restrict__ A16, _Float16* __restrict__ B16)
{
    int i = blockIdx.x;
    int k = threadIdx.x;
    double a = (double)b1[k];
    double b = 0.0;
    for (int c = 0; c < D; ++c) {
        double x = (double)X[i * D + c];              // wave-uniform
        a += x * (double)W1[c * H1 + k];
        b += x * (double)W1[(D + c) * H1 + k];
    }
    A64[i * H1 + k] = a;
    B64[i * H1 + k] = b;
    A16[i * H1 + k] = (_Float16)(float)a;
    B16[i * H1 + k] = (_Float16)(float)b;
}

// ---------------------------------------------------------------------------
// K2: MFMA pair-MLP. Block = 16 i-rows x 64 j-cols = 1024 pairs.
// OPERAND-SWAPPED GEMM: A = W2 (rows = o), B = h = relu(A16[i]+B16[j])
// (cols = pairs). D[row=o_local][col=pair]: each lane (pair = lane&15) holds
// S for o = quad*4+reg+16*nt -> layer-3 reduce is IN-LANE + 2 shfl_xor.
// ---------------------------------------------------------------------------
__global__ __launch_bounds__(256, 3) void pair_mlp_kernel(
    const _Float16* __restrict__ A16, const _Float16* __restrict__ B16,
    const float* __restrict__ W2, const float* __restrict__ b2,
    const float* __restrict__ W3, float* __restrict__ dmat)
{
    __shared__ _Float16 As16[16 * H1PAD];
    __shared__ _Float16 Bs16[64 * H1PAD];
    __shared__ _Float16 W2t[64 * H1PAD];   // transposed: W2t[n][k]

    int tid = threadIdx.x;
    int it = blockIdx.x >> 4;      // 0..63
    int jt = blockIdx.x & 15;      // 0..15
    int ti = it << 4;              // i0
    int tj = jt << 6;              // j0

    // ---- stage A16 rows (16x128 f16): 8 f16 per thread
    {
        int row = tid >> 4;
        int col = (tid & 15) << 3;
        *(half8*)&As16[row * H1PAD + col] =
            *(const half8*)&A16[(size_t)(ti + row) * H1 + col];
    }
    // ---- stage B16 rows (64x128 f16): 32 f16 per thread
    #pragma unroll
    for (int r = 0; r < 4; ++r) {
        int v = tid + r * 256;
        int row = v >> 4;
        int col = (v & 15) << 3;
        *(half8*)&Bs16[row * H1PAD + col] =
            *(const half8*)&B16[(size_t)(tj + row) * H1 + col];
    }
    // ---- stage W2 transposed to f16: W2t[n][k] = W2[k][n]
    #pragma unroll
    for (int r = 0; r < 32; ++r) {
        int idx = tid + r * 256;   // 0..8191
        int k = idx >> 6;
        int n = idx & 63;
        W2t[n * H1PAD + k] = (_Float16)W2[idx];
    }
    __syncthreads();

    int lane = tid & 63;
    int wave = tid >> 6;
    int quad = lane >> 4;          // 0..3
    int m = lane & 15;             // A-frag row (o_local) AND B-frag col (pair)

    // ---- A-frags: W2 fully in registers. afrag[ks][nt]: A[m][k] = W2[k][m+16nt]
    half8 afrag[4][4];
    #pragma unroll
    for (int ks = 0; ks < 4; ++ks)
        #pragma unroll
        for (int nt = 0; nt < 4; ++nt)
            afrag[ks][nt] = *(const half8*)&W2t[(m + 16 * nt) * H1PAD + quad * 8 + 32 * ks];

    // ---- per-lane epilogue constants: this lane's o for (nt,reg) = quad*4+reg+16*nt
    float b2x[4][4], w3x[4][4];
    #pragma unroll
    for (int nt = 0; nt < 4; ++nt)
        #pragma unroll
        for (int reg = 0; reg < 4; ++reg) {
            int o = (quad << 2) + reg + (nt << 4);
            b2x[nt][reg] = b2[o];
            w3x[nt][reg] = W3[o * 2 + 1] - W3[o * 2 + 0];
        }

    const half8 zero8 = {0, 0, 0, 0, 0, 0, 0, 0};

    #pragma unroll 1
    for (int jq = 0; jq < 4; ++jq) {
        int jj0 = jq << 4;
        half8 hb[4];               // this lane's pair j = tj + jj0 + m
        #pragma unroll
        for (int ks = 0; ks < 4; ++ks)
            hb[ks] = *(const half8*)&Bs16[(jj0 + m) * H1PAD + quad * 8 + 32 * ks];

        #pragma unroll 1
        for (int i4 = 0; i4 < 4; ++i4) {
            int ii = (wave << 2) + i4;

            float4v acc[4];
            #pragma unroll
            for (int nt = 0; nt < 4; ++nt)
                acc[nt] = (float4v){b2x[nt][0], b2x[nt][1], b2x[nt][2], b2x[nt][3]};

            #pragma unroll
            for (int ks = 0; ks < 4; ++ks) {
                half8 ha = *(const half8*)&As16[ii * H1PAD + quad * 8 + 32 * ks]; // broadcast
                half8 h = __builtin_elementwise_max(ha + hb[ks], zero8);          // relu
                #pragma unroll
                for (int nt = 0; nt < 4; ++nt)
                    acc[nt] = __builtin_amdgcn_mfma_f32_16x16x32_f16(afrag[ks][nt], h, acc[nt], 0, 0, 0);
            }

            // ---- fused layer 3: in-lane over 16 o's, then quad-sum via shfl_xor
            float s = 0.f;
            #pragma unroll
            for (int nt = 0; nt < 4; ++nt)
                #pragma unroll
                for (int reg = 0; reg < 4; ++reg)
                    s = fmaf(fmaxf(acc[nt][reg], 0.f), w3x[nt][reg], s);
            s += __shfl_xor(s, 16, 64);
            s += __shfl_xor(s, 32, 64);
            if (quad == 0) {
                // 16 lanes store 16 consecutive floats (coalesced 64 B)
                dmat[(size_t)(ti + ii) * N + (tj + jj0 + m)] = s;
            }
        }
    }
}

// ---------------------------------------------------------------------------
// K3: fused epilogue + f64 repair.
// Main phase: D = 0.5*(d[i][j]+d[j][i]) + b3d + (g1-g0) with FAST __logf;
//             out = D > 0; flag |D| < thresh into LDS (no global atomics).
// Repair phase: this block re-resolves its own flags exactly in f64
// (4 waves round-robin, uniform __syncthreads count).
// ---------------------------------------------------------------------------
__global__ __launch_bounds__(256) void epilogue_repair_kernel(
    const float* __restrict__ dmat, const double* __restrict__ A64,
    const double* __restrict__ B64, const float* __restrict__ W2,
    const float* __restrict__ b2, const float* __restrict__ W3,
    const float* __restrict__ b3, const float* __restrict__ u,
    float* __restrict__ out)
{
    __shared__ float T1[32][33];
    __shared__ float T2[32][33];
    __shared__ unsigned int lflags[1024];   // cap = pairs/block: cannot overflow
    __shared__ unsigned int lcnt;
    __shared__ double h1s[4][2][H1];        // 8 KB (per-wave repair scratch)

    int bi = blockIdx.x >> 5;
    int bj = blockIdx.x & 31;
    int i0 = bi * 32, j0 = bj * 32;
    int tid = threadIdx.x;
    int r = tid >> 3;
    int c4 = (tid & 7) << 2;
    if (tid == 0) lcnt = 0;
    *(float4*)&T1[r][c4] = *(const float4*)&dmat[(size_t)(i0 + r) * N + j0 + c4];
    *(float4*)&T2[r][c4] = *(const float4*)&dmat[(size_t)(j0 + r) * N + i0 + c4];
    __syncthreads();

    float b3d = b3[1] - b3[0];
    int a = tid >> 3;
    int b0 = (tid & 7) << 2;
    int ij0 = (i0 + a) * N + (j0 + b0);

    float4 u01 = *(const float4*)&u[((size_t)ij0) * 2];       // pairs q=0,1
    float4 u23 = *(const float4*)&u[((size_t)ij0) * 2 + 4];   // pairs q=2,3
    float uu[8] = {u01.x, u01.y, u01.z, u01.w, u23.x, u23.y, u23.z, u23.w};

    float4 res;
    float* resp = &res.x;
    #pragma unroll
    for (int q = 0; q < 4; ++q) {
        int b = b0 + q;
        // fast-log gumbel: |err| ~1e-5 << FLAG_THRESH margin; flagged pairs
        // are re-resolved exactly below.
        float g0 = -__logf(-__logf(uu[2 * q] + 1e-10f) + 1e-10f);
        float g1 = -__logf(-__logf(uu[2 * q + 1] + 1e-10f) + 1e-10f);
        float Dv = 0.5f * (T1[a][b] + T2[b][a]) + b3d + (g1 - g0);
        resp[q] = Dv > 0.f ? 1.f : 0.f;
        if (fabsf(Dv) < FLAG_THRESH) {
            unsigned int idx = atomicAdd(&lcnt, 1u);   // LDS atomic
            lflags[idx] = (unsigned int)(ij0 + q);
        }
    }
    *(float4*)&out[ij0] = res;

    __syncthreads();
    // ---------------- repair phase (exact f64) ----------------
    unsigned int nl = lcnt;                 // uniform across block
    if (nl == 0) return;

    int lane = tid & 63;
    int wave = tid >> 6;
    double w3dd = (double)W3[lane * 2 + 1] - (double)W3[lane * 2 + 0];
    double b2d = (double)b2[lane];
    int rounds = (int)((nl + 3) >> 2);

    for (int t = 0; t < rounds; ++t) {
        unsigned int f = ((unsigned)t << 2) + wave;
        bool active = f < nl;
        int ij = active ? (int)lflags[f] : 0;
        int i = ij >> 10, j = ij & (N - 1);
        if (active) {   // lane = k (two k's per lane), coalesced f64 loads
            int k0 = lane, k1 = lane + 64;
            double ai0 = A64[(size_t)i * H1 + k0], ai1 = A64[(size_t)i * H1 + k1];
            double aj0 = A64[(size_t)j * H1 + k0], aj1 = A64[(size_t)j * H1 + k1];
            double bi0 = B64[(size_t)i * H1 + k0], bi1 = B64[(size_t)i * H1 + k1];
            double bj0 = B64[(size_t)j * H1 + k0], bj1 = B64[(size_t)j * H1 + k1];
            double v;
            v = ai0 + bj0; h1s[wave][0][k0] = v > 0.0 ? v : 0.0;
            v = ai1 + bj1; h1s[wave][0][k1] = v > 0.0 ? v : 0.0;
            v = aj0 + bi0; h1s[wave][1][k0] = v > 0.0 ? v : 0.0;
            v = aj1 + bi1; h1s[wave][1][k1] = v > 0.0 ? v : 0.0;
        }
        __syncthreads();    // uniform: every thread runs `rounds` iterations
        double sa = b2d, sb = b2d;   // garbage for inactive waves: result discarded
        #pragma unroll 4
        for (int k = 0; k < H1; ++k) {
            double w = (double)W2[k * H2 + lane];   // coalesced, L1-resident
            sa += h1s[wave][0][k] * w;
            sb += h1s[wave][1][k] * w;
        }
        if (sa < 0.0) sa = 0.0;
        if (sb < 0.0) sb = 0.0;
        double da = sa * w3dd;
        double db = sb * w3dd;
        #pragma unroll
        for (int off = 32; off > 0; off >>= 1) {
            da += __shfl_down(da, off, 64);
            db += __shfl_down(db, off, 64);
        }
        if (active && lane == 0) {
            double b3dd = (double)b3[1] - (double)b3[0];
            double u0 = (double)u[(((size_t)ij) << 1) + 0];
            double u1 = (double)u[(((size_t)ij) << 1) + 1];
            double g0 = -log(-log(u0 + 1e-10) + 1e-10);
            double g1 = -log(-log(u1 + 1e-10) + 1e-10);
            double Dv = 0.5 * (da + db) + b3dd + (g1 - g0);
            out[ij] = Dv > 0.0 ? 1.f : 0.f;
        }
        __syncthreads();    // h1s reuse guard
    }
}

// ---------------------------------------------------------------------------
extern "C" void kernel_launch(void* const* d_in, const int* in_sizes, int n_in,
                              void* d_out, int out_size, void* d_ws, size_t ws_size,
                              hipStream_t stream) {
    const float* X  = (const float*)d_in[0];
    const float* W1 = (const float*)d_in[1];
    const float* b1 = (const float*)d_in[2];
    const float* W2 = (const float*)d_in[3];
    const float* b2 = (const float*)d_in[4];
    const float* W3 = (const float*)d_in[5];
    const float* b3 = (const float*)d_in[6];
    const float* u  = (const float*)d_in[7];
    float* out = (float*)d_out;

    // workspace layout (doubles first for alignment)
    double* A64 = (double*)d_ws;                         // 1 MB
    double* B64 = A64 + (size_t)N * H1;                  // 1 MB
    float* dmat = (float*)(B64 + (size_t)N * H1);        // 4 MB
    _Float16* A16 = (_Float16*)(dmat + (size_t)N * N);   // 256 KB
    _Float16* B16 = A16 + (size_t)N * H1;                // 256 KB

    precompute_kernel<<<N, 128, 0, stream>>>(X, W1, b1, A64, B64, A16, B16);
    pair_mlp_kernel<<<(N / 16) * (N / 64), 256, 0, stream>>>(A16, B16, W2, b2, W3, dmat);
    epilogue_repair_kernel<<<(N / 32) * (N / 32), 256, 0, stream>>>(
        dmat, A64, B64, W2, b2, W3, b3, u, out);
}